// Round 3
// baseline (310.744 us; speedup 1.0000x reference)
//
#include <hip/hip_runtime.h>

// Problem constants (B=32, T=4096, D=256, A=128, window=64)
#define TT 4096
#define DD 256
#define AA 128
#define WIN 64

typedef short bf16x8 __attribute__((ext_vector_type(8)));
typedef float f32x4 __attribute__((ext_vector_type(4)));

__device__ __forceinline__ unsigned short f2bf(float f) {
    unsigned int u = __builtin_bit_cast(unsigned int, f);
    u += 0x7FFFu + ((u >> 16) & 1u);   // RTNE
    return (unsigned short)(u >> 16);
}

// ---------------- prep: Wp fp32 -> bf16 (64 KiB, L2-resident) ----------------
__global__ __launch_bounds__(256) void prep_wp(const float* __restrict__ Wp,
                                               unsigned short* __restrict__ wpb) {
    int i = blockIdx.x * 256 + threadIdx.x;   // 32768 total
    wpb[i] = f2bf(Wp[i]);
}

// ---------------- gate: g = sigmoid(Wg . tanh(x Wp^T + bp)) ------------------
// No LDS staging: A-fragments loaded directly from global as 2x float4 and
// converted to bf16 in-register. B (Wp) held in registers, loaded once per
// block. Block = 4 waves; each wave computes all 64 rows x its 32 n-cols.
#define RPB 64   // rows per block

__global__ __launch_bounds__(256) void gate_kernel(
        const float* __restrict__ x, const unsigned short* __restrict__ wpb,
        const float* __restrict__ bp, const float* __restrict__ Wg,
        float* __restrict__ g) {
    __shared__ float psum[4][RPB];
    const int tid  = threadIdx.x;
    const int lane = tid & 63;
    const int wave = tid >> 6;
    const int quad = lane >> 4;
    const int nrow = lane & 15;
    const long row0 = (long)blockIdx.x * RPB;

    // B fragments: wave covers n in [wave*32, wave*32+32)
    bf16x8 bfrag[2][8];
    float bpv[2], wgv[2];
#pragma unroll
    for (int nt = 0; nt < 2; ++nt) {
        int n = wave * 32 + nt * 16 + nrow;
        bpv[nt] = bp[n];
        wgv[nt] = Wg[n];
#pragma unroll
        for (int k0 = 0; k0 < 8; ++k0)
            bfrag[nt][k0] = *reinterpret_cast<const bf16x8*>(
                wpb + n * DD + k0 * 32 + quad * 8);
    }

    f32x4 acc[4][2];
#pragma unroll
    for (int mt = 0; mt < 4; ++mt)
#pragma unroll
        for (int nt = 0; nt < 2; ++nt)
            acc[mt][nt] = (f32x4){0.f, 0.f, 0.f, 0.f};

#pragma unroll
    for (int mt = 0; mt < 4; ++mt) {
        const float* xrow = x + (row0 + mt * 16 + nrow) * DD + quad * 8;
        float4 xa[8][2];
#pragma unroll
        for (int k0 = 0; k0 < 8; ++k0) {
            xa[k0][0] = *reinterpret_cast<const float4*>(xrow + k0 * 32);
            xa[k0][1] = *reinterpret_cast<const float4*>(xrow + k0 * 32 + 4);
        }
#pragma unroll
        for (int k0 = 0; k0 < 8; ++k0) {
            bf16x8 af;
            af[0] = (short)f2bf(xa[k0][0].x); af[1] = (short)f2bf(xa[k0][0].y);
            af[2] = (short)f2bf(xa[k0][0].z); af[3] = (short)f2bf(xa[k0][0].w);
            af[4] = (short)f2bf(xa[k0][1].x); af[5] = (short)f2bf(xa[k0][1].y);
            af[6] = (short)f2bf(xa[k0][1].z); af[7] = (short)f2bf(xa[k0][1].w);
            acc[mt][0] = __builtin_amdgcn_mfma_f32_16x16x32_bf16(af, bfrag[0][k0], acc[mt][0], 0, 0, 0);
            acc[mt][1] = __builtin_amdgcn_mfma_f32_16x16x32_bf16(af, bfrag[1][k0], acc[mt][1], 0, 0, 0);
        }
    }

    // epilogue: tanh -> *Wg -> partial row sums over this wave's 32 n-cols
    float p[4][4];
#pragma unroll
    for (int mt = 0; mt < 4; ++mt)
#pragma unroll
        for (int r = 0; r < 4; ++r) p[mt][r] = 0.f;
#pragma unroll
    for (int nt = 0; nt < 2; ++nt) {
#pragma unroll
        for (int mt = 0; mt < 4; ++mt) {
#pragma unroll
            for (int r = 0; r < 4; ++r) {
                float pre = acc[mt][nt][r] + bpv[nt];
                float e  = __expf(2.0f * pre);
                float th = 1.0f - 2.0f * __builtin_amdgcn_rcpf(e + 1.0f);
                p[mt][r] += th * wgv[nt];
            }
        }
    }
    // reduce over the 16 nrow lanes (lane bits 0..3)
#pragma unroll
    for (int off = 1; off <= 8; off <<= 1)
#pragma unroll
        for (int mt = 0; mt < 4; ++mt)
#pragma unroll
            for (int r = 0; r < 4; ++r)
                p[mt][r] += __shfl_xor(p[mt][r], off, 64);
    if (nrow == 0) {
#pragma unroll
        for (int mt = 0; mt < 4; ++mt)
#pragma unroll
            for (int r = 0; r < 4; ++r)
                psum[wave][mt * 16 + quad * 4 + r] = p[mt][r];   // C-layout row = quad*4+r
    }
    __syncthreads();
    if (tid < RPB) {
        float ssum = psum[0][tid] + psum[1][tid] + psum[2][tid] + psum[3][tid];
        g[row0 + tid] = __builtin_amdgcn_rcpf(1.0f + __expf(-ssum));
    }
}

// ---------------- stream: windowed sum of g*x over win=64, / windowed g-sum --
// Ring-less: S += g[t]x[t] - g[t-64]x[t-64]; subtrahend re-read is an L2 hit
// (64 KB/block rolling window). den fused via scalar recurrence on staged g.
#define TC 256
#define NCHUNK (TT / TC)   // 16

__global__ __launch_bounds__(256) void stream_kernel(
        const float* __restrict__ x, const float* __restrict__ g,
        float* __restrict__ out) {
    __shared__ float gbuf[TC + WIN];
    const int b     = blockIdx.x >> 4;          // NCHUNK = 16
    const int chunk = blockIdx.x & (NCHUNK - 1);
    const int t0    = chunk * TC;
    const int d     = threadIdx.x;
    const float* xb = x + (size_t)b * TT * DD;
    const float* gb = g + (size_t)b * TT;
    float* ob = out + (size_t)b * TT * DD;

    // stage g[t0-64 .. t0+TC-1], zero-padded below 0
    for (int i = d; i < TC + WIN; i += 256) {
        int s = t0 - WIN + i;
        gbuf[i] = (s >= 0) ? gb[s] : 0.f;
    }
    __syncthreads();

    // halo init over [t0-64, t0-1] (g=0 padding kills clamped loads)
    float S = 0.f, Sg = 0.f;
#pragma unroll 16
    for (int i = 0; i < WIN; ++i) {
        int s  = t0 - WIN + i;
        int sc = s < 0 ? 0 : s;
        float gv = gbuf[i];
        S  += gv * xb[(size_t)sc * DD + d];
        Sg += gv;
    }

#pragma unroll 8
    for (int tt = 0; tt < TC; ++tt) {
        int t  = t0 + tt;
        int ts = t - WIN;
        int tsc = ts < 0 ? 0 : ts;
        float gnew = gbuf[WIN + tt];
        float gold = gbuf[tt];
        float vnew = gnew * xb[(size_t)t * DD + d];
        float vold = gold * xb[(size_t)tsc * DD + d];
        S  += vnew - vold;
        Sg += gnew - gold;
        ob[(size_t)t * DD + d] = S * __builtin_amdgcn_rcpf(Sg);
    }
}

extern "C" void kernel_launch(void* const* d_in, const int* in_sizes, int n_in,
                              void* d_out, int out_size, void* d_ws, size_t ws_size,
                              hipStream_t stream) {
    const float* x  = (const float*)d_in[0];
    const float* Wp = (const float*)d_in[1];
    const float* bp = (const float*)d_in[2];
    const float* Wg = (const float*)d_in[3];
    float* out = (float*)d_out;

    // ws layout: [0,64K) Wp bf16 | [64K, 64K+512K) g
    unsigned short* wpb = (unsigned short*)d_ws;
    float* g = (float*)((char*)d_ws + 65536);

    prep_wp<<<AA * DD / 256, 256, 0, stream>>>(Wp, wpb);
    gate_kernel<<<32 * TT / RPB, 256, 0, stream>>>(x, wpb, bp, Wg, g);
    stream_kernel<<<32 * NCHUNK, 256, 0, stream>>>(x, g, out);
}